// Round 7
// baseline (66.095 us; speedup 1.0000x reference)
//
#include <hip/hip_runtime.h>

// HomoHingeLoss via bf16 MFMA GEMM with fused hinge epilogue.
// dot[n,p1,p2] = sum_c desc1[n,c,p1]*desc2[n,c,p2], P=3072, C=256, batch 2.
// Three kernels (NOTE: single-kernel finalize with __threadfence was tried in
// rounds 3/6 and costs ~25us — device-scope release storms the non-coherent
// per-XCD L2s. Keep the separate tiny reduce dispatch.):
//  1) prep: warped grid + f32->bf16 transpose-convert ([n][p][c])
//  2) gemm: 128x128 tile, BK=64, 32KB LDS single-buffer (m97 2-barrier
//     structure), __launch_bounds__(256,5) -> 5 blk/CU, XCD-swizzled bid,
//     fused hinge epilogue with per-tile mask-skip -> per-block partial
//  3) reduce: deterministic 1-block sum -> mean scalar

#define GS 8
#define POS_LAMBDA 250.0f
#define POS_MARGIN 1.0f
#define NEG_MARGIN 0.2f
#define N_ 2
#define C_ 256
#define H_ 48
#define W_ 64
#define P_ (H_ * W_)               // 3072
#define R2_THRESH 56.25f           // (8 - 0.5)^2

#define BM 128
#define BN 128
#define BK 64
#define TM (P_ / BM)               // 24
#define TN (P_ / BN)               // 24
#define GEMM_BLOCKS (N_ * TM * TN) // 1152 = 8 * 144

typedef __attribute__((ext_vector_type(8))) short short8;
typedef __attribute__((ext_vector_type(4))) float floatx4;

__device__ __forceinline__ unsigned short f32_to_bf16(float f) {
    unsigned u = __builtin_bit_cast(unsigned, f);
    unsigned r = (u + 0x7FFFu + ((u >> 16) & 1u)) >> 16;   // RNE
    return (unsigned short)r;
}

__device__ __forceinline__ void load16_to_lds(const void* g, void* l) {
    __builtin_amdgcn_global_load_lds(
        (const __attribute__((address_space(1))) void*)g,
        (__attribute__((address_space(3))) void*)l, 16, 0, 0);
}

// ---------------------------------------------------------------------------
// Kernel 1: blocks 0..11 -> warped grid; blocks 12..779 -> f32 [n][c][p] ->
// bf16 [n][p][c] 64x64 transpose tiles.
__global__ __launch_bounds__(256) void prep_kernel(const float* __restrict__ in1,
                                                   const float* __restrict__ in2,
                                                   const float* __restrict__ homo,
                                                   unsigned short* __restrict__ o1,
                                                   unsigned short* __restrict__ o2,
                                                   float* __restrict__ wg) {
    int bid = blockIdx.x;
    int t = threadIdx.x;

    if (bid < 12) {
        int p = bid * 256 + t;
        float gx = (float)((p & (W_ - 1)) * GS + GS / 2);
        float gy = (float)((p >> 6) * GS + GS / 2);
        float h0 = homo[0], h1 = homo[1], h2 = homo[2];
        float h3 = homo[3], h4 = homo[4], h5 = homo[5];
        float h6 = homo[6], h7 = homo[7], h8 = homo[8];
        float w0 = fmaf(h0, gx, fmaf(h1, gy, h2));
        float w1 = fmaf(h3, gx, fmaf(h4, gy, h5));
        float w2 = fmaf(h6, gx, fmaf(h7, gy, h8));
        wg[2 * p]     = w0 / w2;
        wg[2 * p + 1] = w1 / w2;
        return;
    }

    int b = bid - 12;                     // 0..767
    int d = b & 1;
    int r = b >> 1;                       // 0..383
    int n = r / (48 * 4);
    int r2 = r % (48 * 4);
    int pt = r2 >> 2;                     // p-tile 0..47
    int ct = r2 & 3;                      // c-tile 0..3
    const float* src = (d ? in2 : in1) + ((size_t)n * C_ + ct * 64) * P_ + pt * 64;
    unsigned short* dst = (d ? o2 : o1) + ((size_t)n * P_ + (size_t)pt * 64) * C_ + ct * 64;

    __shared__ unsigned short tile[64][72];   // [p][c], padded rows (144 B)

#pragma unroll
    for (int i = 0; i < 4; ++i) {
        int idx = t + i * 256;            // 0..1023
        int c = idx >> 4;                 // 0..63
        int p4 = (idx & 15) << 2;         // 0,4,...,60
        float4 v = *(const float4*)(src + (size_t)c * P_ + p4);
        tile[p4 + 0][c] = f32_to_bf16(v.x);
        tile[p4 + 1][c] = f32_to_bf16(v.y);
        tile[p4 + 2][c] = f32_to_bf16(v.z);
        tile[p4 + 3][c] = f32_to_bf16(v.w);
    }
    __syncthreads();
#pragma unroll
    for (int i = 0; i < 2; ++i) {
        int idx = t + i * 256;            // 0..511
        int p = idx >> 3;                 // 0..63
        int c8 = (idx & 7) << 3;          // 0,8,...,56
        *(short8*)(dst + (size_t)p * C_ + c8) = *(const short8*)&tile[p][c8];
    }
}

// ---------------------------------------------------------------------------
// Kernel 2: MFMA GEMM, 32KB LDS single-buffer (stage->sync->compute->sync),
// XCD-aware bid swizzle, fused epilogue with mask-skip.
__global__ __launch_bounds__(256, 5) void mfma_hinge_kernel(const unsigned short* __restrict__ bf1,
                                                            const unsigned short* __restrict__ bf2,
                                                            const float* __restrict__ wg,
                                                            const float* __restrict__ homo,
                                                            float* __restrict__ partial) {
    __shared__ __attribute__((aligned(16))) char smem[32768];   // A 16K | B 16K

    // XCD swizzle: block running on XCD (bid%8) takes tile (bid%8)*144 + bid/8
    // -> each XCD's working set = 6 A-panels + 24 B-panels ~ 1.9MB, L2-resident.
    const int bid = (blockIdx.x & 7) * (GEMM_BLOCKS / 8) + (blockIdx.x >> 3);
    const int n   = bid / (TM * TN);
    const int rem = bid % (TM * TN);
    const int bp1 = (rem / TN) * BM;
    const int bp2 = (rem % TN) * BN;
    const unsigned short* A = bf1 + (size_t)n * P_ * C_;
    const unsigned short* B = bf2 + (size_t)n * P_ * C_;

    const int t    = threadIdx.x;
    const int lane = t & 63;
    const int wv   = t >> 6;      // 0..3
    const int wr   = wv >> 1;     // p1 quadrant
    const int wc   = wv & 1;      // p2 quadrant
    const int sub  = lane >> 3;   // 0..7 (row within 8-row chunk)
    const int slot = lane & 7;    // 0..7 (16B slot)
    const int c16  = slot ^ sub;  // inverse-swizzled source slot

    // Per-tile mask-skip bound (scalar homo only; hoisted above the k-loop so
    // the epilogue doesn't stall on s_loads). Warped p2-tile y-range from the
    // 4 tile corners (w affine -> w>0 at corners => w>0 inside; wy
    // linear-fractional -> extremes at vertices). 0.1px safety margin.
    bool skip;
    {
        float h3 = homo[3], h4 = homo[4], h5 = homo[5];
        float h6 = homo[6], h7 = homo[7], h8 = homo[8];
        float y2a = (float)((bp2 >> 6) * GS + GS / 2);
        float y2b = y2a + 8.0f;
        float wymin = 1e30f, wymax = -1e30f;
        bool ok = true;
#pragma unroll
        for (int cidx = 0; cidx < 4; ++cidx) {
            float x = (cidx & 1) ? 508.0f : 4.0f;
            float y = (cidx & 2) ? y2b : y2a;
            float w2 = fmaf(h6, x, fmaf(h7, y, h8));
            ok = ok && (w2 > 1e-6f);
            float wy = fmaf(h3, x, fmaf(h4, y, h5)) / w2;
            wymin = fminf(wymin, wy);
            wymax = fmaxf(wymax, wy);
        }
        float y1min = (float)((bp1 >> 6) * GS + GS / 2);
        float y1max = y1min + 8.0f;
        skip = ok && ((y1max < wymin - 7.6f) || (y1min > wymax + 7.6f));
    }

    floatx4 acc[4][4];
#pragma unroll
    for (int i = 0; i < 4; ++i)
#pragma unroll
        for (int j = 0; j < 4; ++j)
            acc[i][j] = floatx4{0.0f, 0.0f, 0.0f, 0.0f};

    for (int k0 = 0; k0 < C_; k0 += BK) {
        if (k0) __syncthreads();
        // stage: 16 chunks of 1KB per tile; wave wv owns chunks wv*4+i.
#pragma unroll
        for (int i = 0; i < 4; ++i) {
            int chunk = wv * 4 + i;
            int row = chunk * 8 + sub;
            load16_to_lds((const char*)(A + (size_t)(bp1 + row) * C_ + k0) + c16 * 16,
                          smem + chunk * 1024);
        }
#pragma unroll
        for (int i = 0; i < 4; ++i) {
            int chunk = wv * 4 + i;
            int row = chunk * 8 + sub;
            load16_to_lds((const char*)(B + (size_t)(bp2 + row) * C_ + k0) + c16 * 16,
                          smem + 16384 + chunk * 1024);
        }
        __syncthreads();

#pragma unroll
        for (int kk = 0; kk < 2; ++kk) {
            short8 af[4], bfr[4];
#pragma unroll
            for (int i = 0; i < 4; ++i) {
                int row = wr * 64 + i * 16 + (lane & 15);
                int q   = kk * 4 + (lane >> 4);
                int off = row * 128 + ((q ^ (row & 7)) << 4);   // swizzled read
                af[i] = *(const short8*)(smem + off);
            }
#pragma unroll
            for (int j = 0; j < 4; ++j) {
                int row = wc * 64 + j * 16 + (lane & 15);
                int q   = kk * 4 + (lane >> 4);
                int off = row * 128 + ((q ^ (row & 7)) << 4);
                bfr[j] = *(const short8*)(smem + 16384 + off);
            }
#pragma unroll
            for (int i = 0; i < 4; ++i)
#pragma unroll
                for (int j = 0; j < 4; ++j)
                    acc[i][j] = __builtin_amdgcn_mfma_f32_16x16x32_bf16(af[i], bfr[j],
                                                                        acc[i][j], 0, 0, 0);
        }
    }

    const int col   = lane & 15;
    const int rbase = (lane >> 4) * 4;
    float lsum = 0.0f;
    if (skip) {
        // all s==0: loss = max(dot - 0.2, 0)
#pragma unroll
        for (int j = 0; j < 4; ++j)
#pragma unroll
            for (int i = 0; i < 4; ++i)
#pragma unroll
                for (int r = 0; r < 4; ++r)
                    lsum += fmaxf(acc[i][j][r] - NEG_MARGIN, 0.0f);
    } else {
#pragma unroll
        for (int j = 0; j < 4; ++j) {
            int p2 = bp2 + wc * 64 + j * 16 + col;
            float wx = wg[2 * p2], wy = wg[2 * p2 + 1];
#pragma unroll
            for (int i = 0; i < 4; ++i) {
                int p1b = bp1 + wr * 64 + i * 16 + rbase;
#pragma unroll
                for (int r = 0; r < 4; ++r) {
                    int p1 = p1b + r;
                    float gx = (float)((p1 & (W_ - 1)) * GS + GS / 2);
                    float gy = (float)((p1 >> 6) * GS + GS / 2);
                    float dx = gx - wx, dy = gy - wy;
                    float r2 = fmaf(dx, dx, dy * dy);
                    float dot = acc[i][j][r];
                    float pos = fmaxf(POS_MARGIN - dot, 0.0f);
                    float neg = fmaxf(dot - NEG_MARGIN, 0.0f);
                    lsum += (r2 <= R2_THRESH) ? POS_LAMBDA * pos : neg;
                }
            }
        }
    }

    // Block reduction: wave shuffle then cross-wave via smem (reused after a
    // barrier so all waves' LDS fragment reads are complete).
#pragma unroll
    for (int off = 32; off > 0; off >>= 1)
        lsum += __shfl_down(lsum, off, 64);

    float* red = (float*)smem;
    __syncthreads();
    if (lane == 0) red[wv] = lsum;
    __syncthreads();
    if (t == 0) partial[bid] = red[0] + red[1] + red[2] + red[3];
}

// ---------------------------------------------------------------------------
// Kernel 3: deterministic final reduction -> mean.
__global__ __launch_bounds__(256) void reduce_kernel(const float* __restrict__ partial,
                                                     float* __restrict__ out) {
    __shared__ double sd[256];
    int t = threadIdx.x;
    double s = 0.0;
    for (int i = t; i < GEMM_BLOCKS; i += 256) s += (double)partial[i];
    sd[t] = s;
    __syncthreads();
    for (int off = 128; off > 0; off >>= 1) {
        if (t < off) sd[t] += sd[t + off];
        __syncthreads();
    }
    if (t == 0) {
        double cnt = (double)N_ * (double)P_ * (double)P_;
        out[0] = (float)(sd[0] / cnt);
    }
}

// ---------------------------------------------------------------------------
extern "C" void kernel_launch(void* const* d_in, const int* in_sizes, int n_in,
                              void* d_out, int out_size, void* d_ws, size_t ws_size,
                              hipStream_t stream) {
    const float* desc1 = (const float*)d_in[0];
    const float* desc2 = (const float*)d_in[1];
    const float* homo  = (const float*)d_in[2];
    float* out = (float*)d_out;

    unsigned short* b1 = (unsigned short*)d_ws;                 // N*P*C bf16
    unsigned short* b2 = b1 + (size_t)N_ * P_ * C_;             // N*P*C bf16
    float* partial = (float*)(b2 + (size_t)N_ * P_ * C_);       // 1152 f32
    float* wgbuf   = partial + GEMM_BLOCKS;                     // 2*P f32

    prep_kernel<<<780, 256, 0, stream>>>(desc1, desc2, homo, b1, b2, wgbuf);
    mfma_hinge_kernel<<<GEMM_BLOCKS, 256, 0, stream>>>(b1, b2, wgbuf, homo, partial);
    reduce_kernel<<<1, 256, 0, stream>>>(partial, out);
}

// Round 8
// 28.868 us; speedup vs baseline: 2.2895x; 2.2895x over previous
//
#include <hip/hip_runtime.h>

// HomoHingeLoss via bf16 MFMA GEMM with fused hinge epilogue.
// dot[n,p1,p2] = sum_c desc1[n,c,p1]*desc2[n,c,p2], P=3072, C=256, batch 2.
// Three kernels (single-kernel finalize w/ __threadfence costs ~25us on the
// non-coherent per-XCD L2s — rounds 3/6. launch_bounds(256,5) spilled — r7.):
//  1) prep: warped grid + f32->bf16 transpose-convert ([n][p][c])
//  2) gemm: 128x192 tile, BK=64, 40KB LDS single-buffer (m97 2-barrier
//     structure), 768 blocks = 3/CU exactly (one generation, no tail),
//     XCD-swizzled bid, fused hinge epilogue with per-tile mask-skip
//  3) reduce: deterministic 1-block sum -> mean scalar

#define GS 8
#define POS_LAMBDA 250.0f
#define POS_MARGIN 1.0f
#define NEG_MARGIN 0.2f
#define N_ 2
#define C_ 256
#define H_ 48
#define W_ 64
#define P_ (H_ * W_)               // 3072
#define R2_THRESH 56.25f           // (8 - 0.5)^2

#define BM 128
#define BN 192
#define BK 64
#define TM (P_ / BM)               // 24
#define TN (P_ / BN)               // 16
#define GEMM_BLOCKS (N_ * TM * TN) // 768 = 8 * 96 = 3 * 256
#define ANBYTES 16384              // A tile 128x64x2B
#define BNBYTES 24576              // B tile 192x64x2B

typedef __attribute__((ext_vector_type(8))) short short8;
typedef __attribute__((ext_vector_type(4))) float floatx4;

__device__ __forceinline__ unsigned short f32_to_bf16(float f) {
    unsigned u = __builtin_bit_cast(unsigned, f);
    unsigned r = (u + 0x7FFFu + ((u >> 16) & 1u)) >> 16;   // RNE
    return (unsigned short)r;
}

__device__ __forceinline__ void load16_to_lds(const void* g, void* l) {
    __builtin_amdgcn_global_load_lds(
        (const __attribute__((address_space(1))) void*)g,
        (__attribute__((address_space(3))) void*)l, 16, 0, 0);
}

// ---------------------------------------------------------------------------
// Kernel 1: blocks 0..11 -> warped grid; blocks 12..779 -> f32 [n][c][p] ->
// bf16 [n][p][c] 64x64 transpose tiles.
__global__ __launch_bounds__(256) void prep_kernel(const float* __restrict__ in1,
                                                   const float* __restrict__ in2,
                                                   const float* __restrict__ homo,
                                                   unsigned short* __restrict__ o1,
                                                   unsigned short* __restrict__ o2,
                                                   float* __restrict__ wg) {
    int bid = blockIdx.x;
    int t = threadIdx.x;

    if (bid < 12) {
        int p = bid * 256 + t;
        float gx = (float)((p & (W_ - 1)) * GS + GS / 2);
        float gy = (float)((p >> 6) * GS + GS / 2);
        float h0 = homo[0], h1 = homo[1], h2 = homo[2];
        float h3 = homo[3], h4 = homo[4], h5 = homo[5];
        float h6 = homo[6], h7 = homo[7], h8 = homo[8];
        float w0 = fmaf(h0, gx, fmaf(h1, gy, h2));
        float w1 = fmaf(h3, gx, fmaf(h4, gy, h5));
        float w2 = fmaf(h6, gx, fmaf(h7, gy, h8));
        wg[2 * p]     = w0 / w2;
        wg[2 * p + 1] = w1 / w2;
        return;
    }

    int b = bid - 12;                     // 0..767
    int d = b & 1;
    int r = b >> 1;                       // 0..383
    int n = r / (48 * 4);
    int r2 = r % (48 * 4);
    int pt = r2 >> 2;                     // p-tile 0..47
    int ct = r2 & 3;                      // c-tile 0..3
    const float* src = (d ? in2 : in1) + ((size_t)n * C_ + ct * 64) * P_ + pt * 64;
    unsigned short* dst = (d ? o2 : o1) + ((size_t)n * P_ + (size_t)pt * 64) * C_ + ct * 64;

    __shared__ unsigned short tile[64][72];   // [p][c], padded rows (144 B)

#pragma unroll
    for (int i = 0; i < 4; ++i) {
        int idx = t + i * 256;            // 0..1023
        int c = idx >> 4;                 // 0..63
        int p4 = (idx & 15) << 2;         // 0,4,...,60
        float4 v = *(const float4*)(src + (size_t)c * P_ + p4);
        tile[p4 + 0][c] = f32_to_bf16(v.x);
        tile[p4 + 1][c] = f32_to_bf16(v.y);
        tile[p4 + 2][c] = f32_to_bf16(v.z);
        tile[p4 + 3][c] = f32_to_bf16(v.w);
    }
    __syncthreads();
#pragma unroll
    for (int i = 0; i < 2; ++i) {
        int idx = t + i * 256;            // 0..511
        int p = idx >> 3;                 // 0..63
        int c8 = (idx & 7) << 3;          // 0,8,...,56
        *(short8*)(dst + (size_t)p * C_ + c8) = *(const short8*)&tile[p][c8];
    }
}

// ---------------------------------------------------------------------------
// Kernel 2: MFMA GEMM 128x192 tile, 40KB LDS single-buffer
// (stage->sync->compute->sync), XCD-aware bid swizzle, fused epilogue.
// Waves 2x2; wave covers 64 rows x 96 cols = 4x6 16x16 fragments.
__global__ __launch_bounds__(256, 3) void mfma_hinge_kernel(const unsigned short* __restrict__ bf1,
                                                            const unsigned short* __restrict__ bf2,
                                                            const float* __restrict__ wg,
                                                            const float* __restrict__ homo,
                                                            float* __restrict__ partial) {
    __shared__ __attribute__((aligned(16))) char smem[ANBYTES + BNBYTES];  // A|B

    // XCD swizzle: 768 = 8*96; block on XCD (bid%8) takes a contiguous chunk.
    const int bid = (blockIdx.x & 7) * (GEMM_BLOCKS / 8) + (blockIdx.x >> 3);
    const int n   = bid / (TM * TN);
    const int rem = bid % (TM * TN);
    const int bp1 = (rem / TN) * BM;
    const int bp2 = (rem % TN) * BN;
    const unsigned short* A = bf1 + (size_t)n * P_ * C_;
    const unsigned short* B = bf2 + (size_t)n * P_ * C_;

    const int t    = threadIdx.x;
    const int lane = t & 63;
    const int wv   = t >> 6;      // 0..3
    const int wr   = wv >> 1;     // p1 half (64 rows)
    const int wc   = wv & 1;      // p2 half (96 cols)
    const int sub  = lane >> 3;   // 0..7 (row within 8-row chunk)
    const int slot = lane & 7;    // 0..7 (16B slot)
    const int c16  = slot ^ sub;  // inverse-swizzled source slot

    // Per-tile mask-skip bound (scalar homo only). p2 tile spans 3 y-rows ->
    // y2 centers in [y2a, y2a+16]; p1 tile spans 2 y-rows -> [y1min, y1min+8].
    // w affine -> w>0 at corners => w>0 inside; wy linear-fractional ->
    // extremes at vertices. 0.1px safety margin on the 7.5px threshold.
    bool skip;
    {
        float h3 = homo[3], h4 = homo[4], h5 = homo[5];
        float h6 = homo[6], h7 = homo[7], h8 = homo[8];
        float y2a = (float)((bp2 >> 6) * GS + GS / 2);
        float y2b = y2a + 16.0f;
        float wymin = 1e30f, wymax = -1e30f;
        bool ok = true;
#pragma unroll
        for (int cidx = 0; cidx < 4; ++cidx) {
            float x = (cidx & 1) ? 508.0f : 4.0f;
            float y = (cidx & 2) ? y2b : y2a;
            float w2 = fmaf(h6, x, fmaf(h7, y, h8));
            ok = ok && (w2 > 1e-6f);
            float wy = fmaf(h3, x, fmaf(h4, y, h5)) / w2;
            wymin = fminf(wymin, wy);
            wymax = fmaxf(wymax, wy);
        }
        float y1min = (float)((bp1 >> 6) * GS + GS / 2);
        float y1max = y1min + 8.0f;
        skip = ok && ((y1max < wymin - 7.6f) || (y1min > wymax + 7.6f));
    }

    floatx4 acc[4][6];
#pragma unroll
    for (int i = 0; i < 4; ++i)
#pragma unroll
        for (int j = 0; j < 6; ++j)
            acc[i][j] = floatx4{0.0f, 0.0f, 0.0f, 0.0f};

    for (int k0 = 0; k0 < C_; k0 += BK) {
        if (k0) __syncthreads();
        // stage A: 16 chunks of 1KB (8 rows x 128B); wave wv owns 4.
#pragma unroll
        for (int i = 0; i < 4; ++i) {
            int chunk = wv * 4 + i;
            int row = chunk * 8 + sub;
            load16_to_lds((const char*)(A + (size_t)(bp1 + row) * C_ + k0) + c16 * 16,
                          smem + chunk * 1024);
        }
        // stage B: 24 chunks of 1KB; wave wv owns 6.
#pragma unroll
        for (int i = 0; i < 6; ++i) {
            int chunk = wv * 6 + i;
            int row = chunk * 8 + sub;
            load16_to_lds((const char*)(B + (size_t)(bp2 + row) * C_ + k0) + c16 * 16,
                          smem + ANBYTES + chunk * 1024);
        }
        __syncthreads();

#pragma unroll
        for (int kk = 0; kk < 2; ++kk) {
            short8 af[4], bfr[6];
#pragma unroll
            for (int i = 0; i < 4; ++i) {
                int row = wr * 64 + i * 16 + (lane & 15);
                int q   = kk * 4 + (lane >> 4);
                int off = row * 128 + ((q ^ (row & 7)) << 4);   // swizzled read
                af[i] = *(const short8*)(smem + off);
            }
#pragma unroll
            for (int j = 0; j < 6; ++j) {
                int row = wc * 96 + j * 16 + (lane & 15);
                int q   = kk * 4 + (lane >> 4);
                int off = row * 128 + ((q ^ (row & 7)) << 4);
                bfr[j] = *(const short8*)(smem + ANBYTES + off);
            }
#pragma unroll
            for (int i = 0; i < 4; ++i)
#pragma unroll
                for (int j = 0; j < 6; ++j)
                    acc[i][j] = __builtin_amdgcn_mfma_f32_16x16x32_bf16(af[i], bfr[j],
                                                                        acc[i][j], 0, 0, 0);
        }
    }

    const int col   = lane & 15;
    const int rbase = (lane >> 4) * 4;
    float lsum = 0.0f;
    if (skip) {
        // all s==0: loss = max(dot - 0.2, 0)
#pragma unroll
        for (int j = 0; j < 6; ++j)
#pragma unroll
            for (int i = 0; i < 4; ++i)
#pragma unroll
                for (int r = 0; r < 4; ++r)
                    lsum += fmaxf(acc[i][j][r] - NEG_MARGIN, 0.0f);
    } else {
#pragma unroll
        for (int j = 0; j < 6; ++j) {
            int p2 = bp2 + wc * 96 + j * 16 + col;
            float wx = wg[2 * p2], wy = wg[2 * p2 + 1];
#pragma unroll
            for (int i = 0; i < 4; ++i) {
                int p1b = bp1 + wr * 64 + i * 16 + rbase;
#pragma unroll
                for (int r = 0; r < 4; ++r) {
                    int p1 = p1b + r;
                    float gx = (float)((p1 & (W_ - 1)) * GS + GS / 2);
                    float gy = (float)((p1 >> 6) * GS + GS / 2);
                    float dx = gx - wx, dy = gy - wy;
                    float r2 = fmaf(dx, dx, dy * dy);
                    float dot = acc[i][j][r];
                    float pos = fmaxf(POS_MARGIN - dot, 0.0f);
                    float neg = fmaxf(dot - NEG_MARGIN, 0.0f);
                    lsum += (r2 <= R2_THRESH) ? POS_LAMBDA * pos : neg;
                }
            }
        }
    }

    // Block reduction: wave shuffle then cross-wave via smem (after a barrier
    // so all waves' LDS fragment reads are complete).
#pragma unroll
    for (int off = 32; off > 0; off >>= 1)
        lsum += __shfl_down(lsum, off, 64);

    float* red = (float*)smem;
    __syncthreads();
    if (lane == 0) red[wv] = lsum;
    __syncthreads();
    if (t == 0) partial[bid] = red[0] + red[1] + red[2] + red[3];
}

// ---------------------------------------------------------------------------
// Kernel 3: deterministic final reduction -> mean.
__global__ __launch_bounds__(256) void reduce_kernel(const float* __restrict__ partial,
                                                     float* __restrict__ out) {
    __shared__ double sd[256];
    int t = threadIdx.x;
    double s = 0.0;
    for (int i = t; i < GEMM_BLOCKS; i += 256) s += (double)partial[i];
    sd[t] = s;
    __syncthreads();
    for (int off = 128; off > 0; off >>= 1) {
        if (t < off) sd[t] += sd[t + off];
        __syncthreads();
    }
    if (t == 0) {
        double cnt = (double)N_ * (double)P_ * (double)P_;
        out[0] = (float)(sd[0] / cnt);
    }
}

// ---------------------------------------------------------------------------
extern "C" void kernel_launch(void* const* d_in, const int* in_sizes, int n_in,
                              void* d_out, int out_size, void* d_ws, size_t ws_size,
                              hipStream_t stream) {
    const float* desc1 = (const float*)d_in[0];
    const float* desc2 = (const float*)d_in[1];
    const float* homo  = (const float*)d_in[2];
    float* out = (float*)d_out;

    unsigned short* b1 = (unsigned short*)d_ws;                 // N*P*C bf16
    unsigned short* b2 = b1 + (size_t)N_ * P_ * C_;             // N*P*C bf16
    float* partial = (float*)(b2 + (size_t)N_ * P_ * C_);       // 768 f32
    float* wgbuf   = partial + GEMM_BLOCKS;                     // 2*P f32

    prep_kernel<<<780, 256, 0, stream>>>(desc1, desc2, homo, b1, b2, wgbuf);
    mfma_hinge_kernel<<<GEMM_BLOCKS, 256, 0, stream>>>(b1, b2, wgbuf, homo, partial);
    reduce_kernel<<<1, 256, 0, stream>>>(partial, out);
}

// Round 9
// 27.935 us; speedup vs baseline: 2.3661x; 1.0334x over previous
//
#include <hip/hip_runtime.h>

// HomoHingeLoss via bf16 MFMA GEMM with fused hinge epilogue.
// dot[n,p1,p2] = sum_c desc1[n,c,p1]*desc2[n,c,p2], P=3072, C=256, batch 2.
// Journal: r3/r5/r6 sync-structure experiments (fences, stage-ahead dbuf)
// regressed; r7 launch_bounds(256,5) spilled acc to scratch. r4/r8 geometry
// wins. r9: prep LDS transpose writes were 16-way bank conflicts -> XOR slot
// swizzle (4-way). GEMM core = r8 verbatim (128x192, BK=64, 40KB, 768 blocks
// = 3/CU exact, XCD swizzle).
//  1) prep: warped grid + f32->bf16 transpose-convert ([n][p][c])
//  2) gemm: fused hinge epilogue with per-tile mask-skip -> per-block partial
//  3) reduce: deterministic 1-block sum -> mean scalar

#define GS 8
#define POS_LAMBDA 250.0f
#define POS_MARGIN 1.0f
#define NEG_MARGIN 0.2f
#define N_ 2
#define C_ 256
#define H_ 48
#define W_ 64
#define P_ (H_ * W_)               // 3072
#define R2_THRESH 56.25f           // (8 - 0.5)^2

#define BM 128
#define BN 192
#define BK 64
#define TM (P_ / BM)               // 24
#define TN (P_ / BN)               // 16
#define GEMM_BLOCKS (N_ * TM * TN) // 768 = 8 * 96 = 3 * 256
#define ANBYTES 16384              // A tile 128x64x2B
#define BNBYTES 24576              // B tile 192x64x2B

typedef __attribute__((ext_vector_type(8))) short short8;
typedef __attribute__((ext_vector_type(4))) float floatx4;

__device__ __forceinline__ unsigned short f32_to_bf16(float f) {
    unsigned u = __builtin_bit_cast(unsigned, f);
    unsigned r = (u + 0x7FFFu + ((u >> 16) & 1u)) >> 16;   // RNE
    return (unsigned short)r;
}

__device__ __forceinline__ void load16_to_lds(const void* g, void* l) {
    __builtin_amdgcn_global_load_lds(
        (const __attribute__((address_space(1))) void*)g,
        (__attribute__((address_space(3))) void*)l, 16, 0, 0);
}

// ---------------------------------------------------------------------------
// Kernel 1: blocks 0..11 -> warped grid; blocks 12..779 -> f32 [n][c][p] ->
// bf16 [n][p][c] 64x64 transpose tiles.
// LDS tile [64][64] with 16B-slot XOR swizzle: elem (p,c) stored at
// slot = (c>>3) ^ (p&7) ^ ((p>>3)&7), offset slot*8 + (c&7).
// Write instructions spread over 16 banks (4-way) vs 4 banks (16-way) padded.
// Reads gather 8 elems sharing c>>3 -> one contiguous 16B slot.
__global__ __launch_bounds__(256) void prep_kernel(const float* __restrict__ in1,
                                                   const float* __restrict__ in2,
                                                   const float* __restrict__ homo,
                                                   unsigned short* __restrict__ o1,
                                                   unsigned short* __restrict__ o2,
                                                   float* __restrict__ wg) {
    int bid = blockIdx.x;
    int t = threadIdx.x;

    if (bid < 12) {
        int p = bid * 256 + t;
        float gx = (float)((p & (W_ - 1)) * GS + GS / 2);
        float gy = (float)((p >> 6) * GS + GS / 2);
        float h0 = homo[0], h1 = homo[1], h2 = homo[2];
        float h3 = homo[3], h4 = homo[4], h5 = homo[5];
        float h6 = homo[6], h7 = homo[7], h8 = homo[8];
        float w0 = fmaf(h0, gx, fmaf(h1, gy, h2));
        float w1 = fmaf(h3, gx, fmaf(h4, gy, h5));
        float w2 = fmaf(h6, gx, fmaf(h7, gy, h8));
        wg[2 * p]     = w0 / w2;
        wg[2 * p + 1] = w1 / w2;
        return;
    }

    int b = bid - 12;                     // 0..767
    int d = b & 1;
    int r = b >> 1;                       // 0..383
    int n = r / (48 * 4);
    int r2 = r % (48 * 4);
    int pt = r2 >> 2;                     // p-tile 0..47
    int ct = r2 & 3;                      // c-tile 0..3
    const float* src = (d ? in2 : in1) + ((size_t)n * C_ + ct * 64) * P_ + pt * 64;
    unsigned short* dst = (d ? o2 : o1) + ((size_t)n * P_ + (size_t)pt * 64) * C_ + ct * 64;

    __shared__ unsigned short tile[64][64];   // swizzled, 128B rows

#pragma unroll
    for (int i = 0; i < 4; ++i) {
        int idx = t + i * 256;            // 0..1023
        int c = idx >> 4;                 // 0..63
        int p4 = (idx & 15) << 2;         // 0,4,...,60
        float4 v = *(const float4*)(src + (size_t)c * P_ + p4);
        float vv[4] = {v.x, v.y, v.z, v.w};
#pragma unroll
        for (int rr = 0; rr < 4; ++rr) {
            int p = p4 + rr;
            int sw = (p & 7) ^ ((p >> 3) & 7);
            int slot = (c >> 3) ^ sw;
            tile[p][slot * 8 + (c & 7)] = f32_to_bf16(vv[rr]);
        }
    }
    __syncthreads();
#pragma unroll
    for (int i = 0; i < 2; ++i) {
        int idx = t + i * 256;            // 0..511
        int p = idx >> 3;                 // 0..63
        int c8 = idx & 7;                 // slot group 0..7
        int sw = (p & 7) ^ ((p >> 3) & 7);
        short8 val = *(const short8*)&tile[p][(c8 ^ sw) * 8];
        *(short8*)(dst + (size_t)p * C_ + c8 * 8) = val;
    }
}

// ---------------------------------------------------------------------------
// Kernel 2: MFMA GEMM 128x192 tile, 40KB LDS single-buffer
// (stage->sync->compute->sync), XCD-aware bid swizzle, fused epilogue.
// Waves 2x2; wave covers 64 rows x 96 cols = 4x6 16x16 fragments.
__global__ __launch_bounds__(256, 3) void mfma_hinge_kernel(const unsigned short* __restrict__ bf1,
                                                            const unsigned short* __restrict__ bf2,
                                                            const float* __restrict__ wg,
                                                            const float* __restrict__ homo,
                                                            float* __restrict__ partial) {
    __shared__ __attribute__((aligned(16))) char smem[ANBYTES + BNBYTES];  // A|B

    // XCD swizzle: 768 = 8*96; block on XCD (bid%8) takes a contiguous chunk.
    const int bid = (blockIdx.x & 7) * (GEMM_BLOCKS / 8) + (blockIdx.x >> 3);
    const int n   = bid / (TM * TN);
    const int rem = bid % (TM * TN);
    const int bp1 = (rem / TN) * BM;
    const int bp2 = (rem % TN) * BN;
    const unsigned short* A = bf1 + (size_t)n * P_ * C_;
    const unsigned short* B = bf2 + (size_t)n * P_ * C_;

    const int t    = threadIdx.x;
    const int lane = t & 63;
    const int wv   = t >> 6;      // 0..3
    const int wr   = wv >> 1;     // p1 half (64 rows)
    const int wc   = wv & 1;      // p2 half (96 cols)
    const int sub  = lane >> 3;   // 0..7 (row within 8-row chunk)
    const int slot = lane & 7;    // 0..7 (16B slot)
    const int c16  = slot ^ sub;  // inverse-swizzled source slot

    // Per-tile mask-skip bound (scalar homo only). p2 tile spans 3 y-rows ->
    // y2 centers in [y2a, y2a+16]; p1 tile spans 2 y-rows -> [y1min, y1min+8].
    // w affine -> w>0 at corners => w>0 inside; wy linear-fractional ->
    // extremes at vertices. 0.1px safety margin on the 7.5px threshold.
    bool skip;
    {
        float h3 = homo[3], h4 = homo[4], h5 = homo[5];
        float h6 = homo[6], h7 = homo[7], h8 = homo[8];
        float y2a = (float)((bp2 >> 6) * GS + GS / 2);
        float y2b = y2a + 16.0f;
        float wymin = 1e30f, wymax = -1e30f;
        bool ok = true;
#pragma unroll
        for (int cidx = 0; cidx < 4; ++cidx) {
            float x = (cidx & 1) ? 508.0f : 4.0f;
            float y = (cidx & 2) ? y2b : y2a;
            float w2 = fmaf(h6, x, fmaf(h7, y, h8));
            ok = ok && (w2 > 1e-6f);
            float wy = fmaf(h3, x, fmaf(h4, y, h5)) / w2;
            wymin = fminf(wymin, wy);
            wymax = fmaxf(wymax, wy);
        }
        float y1min = (float)((bp1 >> 6) * GS + GS / 2);
        float y1max = y1min + 8.0f;
        skip = ok && ((y1max < wymin - 7.6f) || (y1min > wymax + 7.6f));
    }

    floatx4 acc[4][6];
#pragma unroll
    for (int i = 0; i < 4; ++i)
#pragma unroll
        for (int j = 0; j < 6; ++j)
            acc[i][j] = floatx4{0.0f, 0.0f, 0.0f, 0.0f};

    for (int k0 = 0; k0 < C_; k0 += BK) {
        if (k0) __syncthreads();
        // stage A: 16 chunks of 1KB (8 rows x 128B); wave wv owns 4.
#pragma unroll
        for (int i = 0; i < 4; ++i) {
            int chunk = wv * 4 + i;
            int row = chunk * 8 + sub;
            load16_to_lds((const char*)(A + (size_t)(bp1 + row) * C_ + k0) + c16 * 16,
                          smem + chunk * 1024);
        }
        // stage B: 24 chunks of 1KB; wave wv owns 6.
#pragma unroll
        for (int i = 0; i < 6; ++i) {
            int chunk = wv * 6 + i;
            int row = chunk * 8 + sub;
            load16_to_lds((const char*)(B + (size_t)(bp2 + row) * C_ + k0) + c16 * 16,
                          smem + ANBYTES + chunk * 1024);
        }
        __syncthreads();

#pragma unroll
        for (int kk = 0; kk < 2; ++kk) {
            short8 af[4], bfr[6];
#pragma unroll
            for (int i = 0; i < 4; ++i) {
                int row = wr * 64 + i * 16 + (lane & 15);
                int q   = kk * 4 + (lane >> 4);
                int off = row * 128 + ((q ^ (row & 7)) << 4);   // swizzled read
                af[i] = *(const short8*)(smem + off);
            }
#pragma unroll
            for (int j = 0; j < 6; ++j) {
                int row = wc * 96 + j * 16 + (lane & 15);
                int q   = kk * 4 + (lane >> 4);
                int off = row * 128 + ((q ^ (row & 7)) << 4);
                bfr[j] = *(const short8*)(smem + ANBYTES + off);
            }
#pragma unroll
            for (int i = 0; i < 4; ++i)
#pragma unroll
                for (int j = 0; j < 6; ++j)
                    acc[i][j] = __builtin_amdgcn_mfma_f32_16x16x32_bf16(af[i], bfr[j],
                                                                        acc[i][j], 0, 0, 0);
        }
    }

    const int col   = lane & 15;
    const int rbase = (lane >> 4) * 4;
    float lsum = 0.0f;
    if (skip) {
        // all s==0: loss = max(dot - 0.2, 0)
#pragma unroll
        for (int j = 0; j < 6; ++j)
#pragma unroll
            for (int i = 0; i < 4; ++i)
#pragma unroll
                for (int r = 0; r < 4; ++r)
                    lsum += fmaxf(acc[i][j][r] - NEG_MARGIN, 0.0f);
    } else {
#pragma unroll
        for (int j = 0; j < 6; ++j) {
            int p2 = bp2 + wc * 96 + j * 16 + col;
            float wx = wg[2 * p2], wy = wg[2 * p2 + 1];
#pragma unroll
            for (int i = 0; i < 4; ++i) {
                int p1b = bp1 + wr * 64 + i * 16 + rbase;
#pragma unroll
                for (int r = 0; r < 4; ++r) {
                    int p1 = p1b + r;
                    float gx = (float)((p1 & (W_ - 1)) * GS + GS / 2);
                    float gy = (float)((p1 >> 6) * GS + GS / 2);
                    float dx = gx - wx, dy = gy - wy;
                    float r2 = fmaf(dx, dx, dy * dy);
                    float dot = acc[i][j][r];
                    float pos = fmaxf(POS_MARGIN - dot, 0.0f);
                    float neg = fmaxf(dot - NEG_MARGIN, 0.0f);
                    lsum += (r2 <= R2_THRESH) ? POS_LAMBDA * pos : neg;
                }
            }
        }
    }

    // Block reduction: wave shuffle then cross-wave via smem. The k-loop's
    // final __syncthreads already ordered all fragment reads before reuse.
#pragma unroll
    for (int off = 32; off > 0; off >>= 1)
        lsum += __shfl_down(lsum, off, 64);

    float* red = (float*)smem;
    if (lane == 0) red[wv] = lsum;
    __syncthreads();
    if (t == 0) partial[bid] = red[0] + red[1] + red[2] + red[3];
}

// ---------------------------------------------------------------------------
// Kernel 3: deterministic final reduction -> mean.
__global__ __launch_bounds__(256) void reduce_kernel(const float* __restrict__ partial,
                                                     float* __restrict__ out) {
    __shared__ double sd[256];
    int t = threadIdx.x;
    double s = 0.0;
    for (int i = t; i < GEMM_BLOCKS; i += 256) s += (double)partial[i];
    sd[t] = s;
    __syncthreads();
    for (int off = 128; off > 0; off >>= 1) {
        if (t < off) sd[t] += sd[t + off];
        __syncthreads();
    }
    if (t == 0) {
        double cnt = (double)N_ * (double)P_ * (double)P_;
        out[0] = (float)(sd[0] / cnt);
    }
}

// ---------------------------------------------------------------------------
extern "C" void kernel_launch(void* const* d_in, const int* in_sizes, int n_in,
                              void* d_out, int out_size, void* d_ws, size_t ws_size,
                              hipStream_t stream) {
    const float* desc1 = (const float*)d_in[0];
    const float* desc2 = (const float*)d_in[1];
    const float* homo  = (const float*)d_in[2];
    float* out = (float*)d_out;

    unsigned short* b1 = (unsigned short*)d_ws;                 // N*P*C bf16
    unsigned short* b2 = b1 + (size_t)N_ * P_ * C_;             // N*P*C bf16
    float* partial = (float*)(b2 + (size_t)N_ * P_ * C_);       // 768 f32
    float* wgbuf   = partial + GEMM_BLOCKS;                     // 2*P f32

    prep_kernel<<<780, 256, 0, stream>>>(desc1, desc2, homo, b1, b2, wgbuf);
    mfma_hinge_kernel<<<GEMM_BLOCKS, 256, 0, stream>>>(b1, b2, wgbuf, homo, partial);
    reduce_kernel<<<1, 256, 0, stream>>>(partial, out);
}